// Round 6
// baseline (732.274 us; speedup 1.0000x reference)
//
#include <hip/hip_runtime.h>
#include <hip/hip_cooperative_groups.h>

namespace cg = cooperative_groups;

#define CIN   64
#define COUT  64
#define TT    12
#define FEAT  (CIN * TT)   // 768
#define QROW  (FEAT / 4)   // 192 uint2 (4 bf16) per row

typedef unsigned int uint32;
typedef unsigned long long u64;
typedef float  __attribute__((ext_vector_type(4))) f32x4;

#define DEG_SCALE 1048576.0f   // 2^20 fixed point for edge-weight sums

// ---------------- single cooperative setup kernel ----------------
// A1: zero deg64 + f32->bf16 convert   | sync
// A2: weighted-degree atomics          | sync
// B : dis + per-block count partials   | sync
// C : scan -> rowptr/cursor            | sync
// D : scatter edges into CSR
__global__ __launch_bounds__(256, 4) void k_setup(
    const f32x4* __restrict__ x, uint2* __restrict__ xh, int nquads,
    const int* __restrict__ src, const int* __restrict__ dst,
    const float* __restrict__ ea,
    u64* __restrict__ deg64, float* __restrict__ dis,
    int* __restrict__ rowptr, int* __restrict__ cursor,
    int* __restrict__ partial, int2* __restrict__ csr,
    int N, int E, int nb_n)
{
    cg::grid_group grid = cg::this_grid();
    const int t    = threadIdx.x;
    const int bid  = blockIdx.x;
    const int gtid = bid * 256 + t;
    const int gsz  = gridDim.x * 256;

    // ---- A1: zero deg64; bf16 convert (no downstream dep until k_conv) ----
    for (int i = gtid; i < N; i += gsz) deg64[i] = 0;
    if (xh != nullptr) {
        for (int i = gtid; i < nquads; i += gsz) {
            f32x4 v = __builtin_nontemporal_load(&x[i]);   // read-once stream
            uint32 u0 = __float_as_uint(v.x), u1 = __float_as_uint(v.y);
            uint32 u2 = __float_as_uint(v.z), u3 = __float_as_uint(v.w);
            u0 = (u0 + 0x7fffu + ((u0 >> 16) & 1)) >> 16;
            u1 = (u1 + 0x7fffu + ((u1 >> 16) & 1)) >> 16;
            u2 = (u2 + 0x7fffu + ((u2 >> 16) & 1)) >> 16;
            u3 = (u3 + 0x7fffu + ((u3 >> 16) & 1)) >> 16;
            uint2 o; o.x = u0 | (u1 << 16); o.y = u2 | (u3 << 16);
            xh[i] = o;
        }
    }
    grid.sync();

    // ---- A2: weighted-degree atomics (cnt hi32, fixed-point ea-sum lo32) ----
    for (int e = gtid; e < E; e += gsz) {
        u64 v = ((u64)1 << 32) | (u64)(uint32)(ea[e] * DEG_SCALE + 0.5f);
        atomicAdd(&deg64[dst[e]], v);
    }
    grid.sync();

    // ---- B: dis = rsqrt(1 + sum_ea); block-reduce counts -> partial[] ----
    __shared__ int red[256];
    if (bid < nb_n) {
        int i = bid * 256 + t;
        int cnt = 0;
        if (i < N) {
            u64 v = deg64[i];
            cnt = (int)(v >> 32);
            dis[i] = rsqrtf(1.0f + (float)(uint32)v * (1.0f / DEG_SCALE));
        }
        red[t] = cnt;
        __syncthreads();
        for (int off = 128; off > 0; off >>= 1) {
            if (t < off) red[t] += red[t + off];
            __syncthreads();
        }
        if (t == 0) partial[bid] = red[0];
    }
    grid.sync();

    // ---- C: per-element scan + redundant partial prefix -> rowptr, cursor ----
    // requires nb_n <= 256
    __shared__ int tmp[256];
    __shared__ int pred[256];
    if (bid < nb_n) {
        int i = bid * 256 + t;
        int pv = (t < nb_n) ? partial[t] : 0;
        pred[t] = (t < bid) ? pv : 0;
        int v = (i < N) ? (int)(deg64[i] >> 32) : 0;
        tmp[t] = v;
        __syncthreads();
        for (int off = 128; off > 0; off >>= 1) {
            if (t < off) pred[t] += pred[t + off];
            __syncthreads();
        }
        for (int off = 1; off < 256; off <<= 1) {
            int u = (t >= off) ? tmp[t - off] : 0;
            __syncthreads();
            tmp[t] += u;
            __syncthreads();
        }
        int excl = tmp[t] - v + pred[0];
        if (i < N) { rowptr[i] = excl; cursor[i] = excl; }
        if (bid == nb_n - 1 && t == 255) rowptr[N] = pred[0] + tmp[255];
    }
    grid.sync();

    // ---- D: scatter edges into CSR slots ----
    for (int e = gtid; e < E; e += gsz) {
        int s = src[e], d = dst[e];
        int pos = atomicAdd(&cursor[d], 1);
        float w = dis[s] * ea[e] * dis[d];
        int2 p; p.x = s; p.y = __float_as_int(w);
        csr[pos] = p;
    }
}

// ---------- fused aggregate + GEMM + bias + ReLU (UNCHANGED from R5) ----------
// one block per node, 192 threads; thread t owns features [4t, 4t+4)
template <int BF16>
__global__ __launch_bounds__(192) void k_conv(
    const void* __restrict__ xsrc, const float* __restrict__ W,
    const float* __restrict__ b, const float* __restrict__ dis,
    const int* __restrict__ rowptr, const int2* __restrict__ csr,
    float* __restrict__ out)
{
    __shared__ float sAgg[FEAT];   // 3 KB
    __shared__ int2  sE[192];      // 1.5 KB
    __shared__ float sB[COUT];

    const int n = blockIdx.x;
    const int t = threadIdx.x;
    if (t < COUT) sB[t] = b[t];

    const int start = rowptr[n];
    const int end   = rowptr[n + 1];
    const float dn  = dis[n];
    const float selfw = dn * dn;

    float a0, a1, a2, a3;
    if (BF16) {
        const uint2* xb = (const uint2*)xsrc;
        uint2 v = xb[(size_t)n * QROW + t];
        a0 = selfw * __uint_as_float(v.x << 16);
        a1 = selfw * __uint_as_float(v.x & 0xffff0000u);
        a2 = selfw * __uint_as_float(v.y << 16);
        a3 = selfw * __uint_as_float(v.y & 0xffff0000u);
    } else {
        const f32x4* xb = (const f32x4*)xsrc;
        f32x4 v = xb[(size_t)n * QROW + t];
        a0 = selfw * v.x; a1 = selfw * v.y; a2 = selfw * v.z; a3 = selfw * v.w;
    }

    for (int base = start; base < end; base += 192) {
        int cnt = end - base; if (cnt > 192) cnt = 192;
        __syncthreads();
        if (t < cnt) sE[t] = csr[base + t];
        __syncthreads();
        for (int j = 0; j < cnt; ++j) {
            int s    = sE[j].x;
            float w  = __int_as_float(sE[j].y);
            if (BF16) {
                const uint2* xb = (const uint2*)xsrc;
                uint2 v = xb[(size_t)s * QROW + t];
                a0 = fmaf(w, __uint_as_float(v.x << 16),         a0);
                a1 = fmaf(w, __uint_as_float(v.x & 0xffff0000u), a1);
                a2 = fmaf(w, __uint_as_float(v.y << 16),         a2);
                a3 = fmaf(w, __uint_as_float(v.y & 0xffff0000u), a3);
            } else {
                const f32x4* xb = (const f32x4*)xsrc;
                f32x4 v = xb[(size_t)s * QROW + t];
                a0 = fmaf(w, v.x, a0); a1 = fmaf(w, v.y, a1);
                a2 = fmaf(w, v.z, a2); a3 = fmaf(w, v.w, a3);
            }
        }
    }

    float4 av; av.x = a0; av.y = a1; av.z = a2; av.w = a3;
    *((float4*)&sAgg[4 * t]) = av;
    __syncthreads();

    const int co  = t & 63;
    const int tg  = t >> 6;              // wave-uniform
    const int tt0 = tg * 4;
    float o0 = sB[co], o1 = o0, o2 = o0, o3 = o0;
#pragma unroll
    for (int c = 0; c < CIN; ++c) {
        float wv = W[c * COUT + co];     // hot 16 KB in L1/L2
        o0 = fmaf(wv, sAgg[c * TT + tt0    ], o0);
        o1 = fmaf(wv, sAgg[c * TT + tt0 + 1], o1);
        o2 = fmaf(wv, sAgg[c * TT + tt0 + 2], o2);
        o3 = fmaf(wv, sAgg[c * TT + tt0 + 3], o3);
    }
    o0 = fmaxf(o0, 0.0f); o1 = fmaxf(o1, 0.0f);
    o2 = fmaxf(o2, 0.0f); o3 = fmaxf(o3, 0.0f);

    __syncthreads();
    float4 ov; ov.x = o0; ov.y = o1; ov.z = o2; ov.w = o3;
    *((float4*)&sAgg[co * TT + tt0]) = ov;
    __syncthreads();
    f32x4 r = *((const f32x4*)&sAgg[4 * t]);
    __builtin_nontemporal_store(r, (f32x4*)(out + (size_t)n * FEAT + 4 * t));
}

// ---------- launch ----------
extern "C" void kernel_launch(void* const* d_in, const int* in_sizes, int n_in,
                              void* d_out, int out_size, void* d_ws, size_t ws_size,
                              hipStream_t stream) {
    const float* x   = (const float*)d_in[0];
    const int*   ei  = (const int*)d_in[1];
    const float* ea  = (const float*)d_in[2];
    const float* W   = (const float*)d_in[3];
    const float* b   = (const float*)d_in[4];
    float* out = (float*)d_out;

    const int E = in_sizes[2];
    const int N = in_sizes[0] / FEAT;
    const int* src = ei;
    const int* dst = ei + E;

    size_t off = 0;
    char* ws = (char*)d_ws;
    auto alloc = [&](size_t bytes) -> char* {
        char* p = ws + off;
        off = (off + bytes + 15) & ~(size_t)15;
        return p;
    };
    u64*   deg64   = (u64*)  alloc((size_t)N * 8);
    float* dis     = (float*)alloc((size_t)N * 4);
    int*   rowptr  = (int*)  alloc((size_t)(N + 1) * 4);
    int*   cursor  = (int*)  alloc((size_t)N * 4);
    int*   partial = (int*)  alloc(4096);
    int2*  csr     = (int2*) alloc((size_t)E * 8);
    unsigned short* xh = (unsigned short*)alloc((size_t)N * FEAT * 2);
    const bool use_bf16 = (off <= ws_size);

    int nb_n   = (N + 255) / 256;        // 196 for N=50000; must be <= 256
    int nquads = (N * FEAT) / 4;

    // cooperative setup: 1024 blocks x 256 thr, guaranteed co-resident at
    // __launch_bounds__(256,4) (>= 4 blocks/CU x 256 CUs)
    {
        const f32x4* xp = (const f32x4*)x;
        uint2* xhp = use_bf16 ? (uint2*)xh : nullptr;
        const int* srcp = src; const int* dstp = dst;
        const float* eap = ea;
        int Nv = N, Ev = E, nbv = nb_n, nq = nquads;
        void* params[] = {
            (void*)&xp, (void*)&xhp, (void*)&nq,
            (void*)&srcp, (void*)&dstp, (void*)&eap,
            (void*)&deg64, (void*)&dis, (void*)&rowptr, (void*)&cursor,
            (void*)&partial, (void*)&csr,
            (void*)&Nv, (void*)&Ev, (void*)&nbv
        };
        (void)hipLaunchCooperativeKernel((const void*)k_setup,
                                         dim3(1024), dim3(256),
                                         params, 0, stream);
    }

    if (use_bf16)
        k_conv<1><<<N, 192, 0, stream>>>(xh, W, b, dis, rowptr, csr, out);
    else
        k_conv<0><<<N, 192, 0, stream>>>(x,  W, b, dis, rowptr, csr, out);
}

// Round 7
// 422.507 us; speedup vs baseline: 1.7332x; 1.7332x over previous
//
#include <hip/hip_runtime.h>

#define CIN   64
#define COUT  64
#define TT    12
#define FEAT  (CIN * TT)   // 768
#define QROW  (FEAT / 4)   // 192 uint2 (4 bf16) per row

typedef unsigned int uint32;
typedef unsigned long long u64;
typedef float  __attribute__((ext_vector_type(4))) f32x4;

#define DEG_SCALE 1048576.0f   // 2^20 fixed point for edge-weight sums

// ---------- fused: y = bf16(x @ W) (blocks [0,nbY)) + degree atomics ----------
// y-GEMM: 384 thr = 2 sub-groups of 192; sub-group handles one node.
// thread tl in [0,192): co = tl/3, ttg = tl%3 -> computes y[n, co*12 + ttg*4 .. +3]
__global__ __launch_bounds__(384) void k_ygemm_deg(
    const float* __restrict__ x, const float* __restrict__ W,
    unsigned short* __restrict__ yh, int Nnodes, int nbY,
    const int* __restrict__ dst, const float* __restrict__ ea,
    u64* __restrict__ deg64, int e_cnt)
{
    const int bid = blockIdx.x;
    const int t   = threadIdx.x;
    if (bid < nbY) {
        __shared__ float sW[CIN * COUT];   // 16 KB
        __shared__ float sx[2][FEAT];      // 6 KB
        for (int i = t; i < CIN * COUT; i += 384) sW[i] = W[i];
        const int sub = t / 192;
        const int tl  = t - sub * 192;
        const int co  = tl / 3;            // 0..63
        const int ttg = tl - co * 3;       // 0..2
        const int tb  = ttg * 4;
        __syncthreads();
        for (int n0 = bid * 2; n0 < Nnodes; n0 += nbY * 2) {
            int n = n0 + sub;
            if (n < Nnodes) {
                const f32x4* xr = (const f32x4*)(x + (size_t)n * FEAT);
                *((f32x4*)&sx[sub][tl * 4]) = xr[tl];   // stage full 3 KB row
            }
            __syncthreads();
            if (n < Nnodes) {
                float o0 = 0, o1 = 0, o2 = 0, o3 = 0;
#pragma unroll
                for (int c = 0; c < CIN; ++c) {
                    float wv = sW[c * COUT + co];
                    o0 = fmaf(wv, sx[sub][c * TT + tb    ], o0);
                    o1 = fmaf(wv, sx[sub][c * TT + tb + 1], o1);
                    o2 = fmaf(wv, sx[sub][c * TT + tb + 2], o2);
                    o3 = fmaf(wv, sx[sub][c * TT + tb + 3], o3);
                }
                uint32 u0 = __float_as_uint(o0), u1 = __float_as_uint(o1);
                uint32 u2 = __float_as_uint(o2), u3 = __float_as_uint(o3);
                u0 = (u0 + 0x7fffu + ((u0 >> 16) & 1)) >> 16;
                u1 = (u1 + 0x7fffu + ((u1 >> 16) & 1)) >> 16;
                u2 = (u2 + 0x7fffu + ((u2 >> 16) & 1)) >> 16;
                u3 = (u3 + 0x7fffu + ((u3 >> 16) & 1)) >> 16;
                uint2 o; o.x = u0 | (u1 << 16); o.y = u2 | (u3 << 16);
                ((uint2*)(yh + (size_t)n * FEAT))[co * 3 + ttg] = o;
            }
            __syncthreads();
        }
    } else {
        int e = (bid - nbY) * 384 + t;
        if (e < e_cnt) {
            u64 v = ((u64)1 << 32) | (u64)(uint32)(ea[e] * DEG_SCALE + 0.5f);
            atomicAdd(&deg64[dst[e]], v);
        }
    }
}

// ---------- dis = rsqrt(1 + sum_ea); block-reduce cnt into partial[] ----------
__global__ __launch_bounds__(256) void k_disred(const u64* __restrict__ deg64,
                                                float* __restrict__ dis,
                                                int* __restrict__ partial, int n) {
    __shared__ int red[256];
    int t = threadIdx.x;
    int i = blockIdx.x * 256 + t;
    int cnt = 0;
    if (i < n) {
        u64 v = deg64[i];
        cnt = (int)(v >> 32);
        dis[i] = rsqrtf(1.0f + (float)(uint32)v * (1.0f / DEG_SCALE));
    }
    red[t] = cnt;
    __syncthreads();
    for (int off = 128; off > 0; off >>= 1) {
        if (t < off) red[t] += red[t + off];
        __syncthreads();
    }
    if (t == 0) partial[blockIdx.x] = red[0];
}

// ---------- per-element scan; each block redundantly reduces partial[] ----------
// nb (number of partials) must be <= 256
__global__ __launch_bounds__(256) void k_scanwrite(const u64* __restrict__ deg64,
                                                   const int* __restrict__ partial,
                                                   int nb,
                                                   int* __restrict__ rowptr,
                                                   int* __restrict__ cursor, int n) {
    __shared__ int tmp[256];
    __shared__ int pred[256];
    int t = threadIdx.x;
    int bid = blockIdx.x;
    int i = bid * 256 + t;

    int pv = (t < nb) ? partial[t] : 0;
    pred[t] = (t < bid) ? pv : 0;
    int v = (i < n) ? (int)(deg64[i] >> 32) : 0;
    tmp[t] = v;
    __syncthreads();
    for (int off = 128; off > 0; off >>= 1) {
        if (t < off) pred[t] += pred[t + off];
        __syncthreads();
    }
    for (int off = 1; off < 256; off <<= 1) {
        int u = (t >= off) ? tmp[t - off] : 0;
        __syncthreads();
        tmp[t] += u;
        __syncthreads();
    }
    int blockOff = pred[0];
    int excl = tmp[t] - v + blockOff;
    if (i < n) { rowptr[i] = excl; cursor[i] = excl; }
    if (bid == nb - 1 && t == 255) rowptr[n] = blockOff + tmp[255];
}

// ---------- scatter edges into CSR slots ----------
__global__ void k_fill(const int* __restrict__ src, const int* __restrict__ dst,
                       const float* __restrict__ ea, const float* __restrict__ dis,
                       int* __restrict__ cursor, int2* __restrict__ csr, int e_cnt) {
    int e = blockIdx.x * blockDim.x + threadIdx.x;
    if (e < e_cnt) {
        int s = src[e], d = dst[e];
        int pos = atomicAdd(&cursor[d], 1);
        float w = dis[s] * ea[e] * dis[d];
        int2 p; p.x = s; p.y = __float_as_int(w);
        csr[pos] = p;
    }
}

// ---------- gather-aggregate over y + bias + ReLU (no GEMM epilogue) ----------
// one block per node, 192 threads; thread t owns features [4t, 4t+4)
__global__ __launch_bounds__(192) void k_conv_y(
    const unsigned short* __restrict__ yh, const float* __restrict__ b,
    const float* __restrict__ dis, const int* __restrict__ rowptr,
    const int2* __restrict__ csr, float* __restrict__ out)
{
    __shared__ int2 sE[192];   // 1.5 KB — only LDS in the kernel

    const int n = blockIdx.x;
    const int t = threadIdx.x;
    const int start = rowptr[n];
    const int end   = rowptr[n + 1];
    const float dn  = dis[n];
    const float selfw = dn * dn;

    const uint2* yb = (const uint2*)yh;
    uint2 v = yb[(size_t)n * QROW + t];
    float a0 = selfw * __uint_as_float(v.x << 16);
    float a1 = selfw * __uint_as_float(v.x & 0xffff0000u);
    float a2 = selfw * __uint_as_float(v.y << 16);
    float a3 = selfw * __uint_as_float(v.y & 0xffff0000u);

    for (int base = start; base < end; base += 192) {
        int cnt = end - base; if (cnt > 192) cnt = 192;
        __syncthreads();
        if (t < cnt) sE[t] = csr[base + t];
        __syncthreads();
        for (int j = 0; j < cnt; ++j) {
            int s    = sE[j].x;
            float w  = __int_as_float(sE[j].y);
            uint2 u = yb[(size_t)s * QROW + t];
            a0 = fmaf(w, __uint_as_float(u.x << 16),         a0);
            a1 = fmaf(w, __uint_as_float(u.x & 0xffff0000u), a1);
            a2 = fmaf(w, __uint_as_float(u.y << 16),         a2);
            a3 = fmaf(w, __uint_as_float(u.y & 0xffff0000u), a3);
        }
    }

    const int f = 4 * t;
    f32x4 r;
    r.x = fmaxf(a0 + b[ f      / 12], 0.0f);
    r.y = fmaxf(a1 + b[(f + 1) / 12], 0.0f);
    r.z = fmaxf(a2 + b[(f + 2) / 12], 0.0f);
    r.w = fmaxf(a3 + b[(f + 3) / 12], 0.0f);
    __builtin_nontemporal_store(r, (f32x4*)(out + (size_t)n * FEAT + f));
}

// ---------- fallback (ws too small): fp32 gather of x + GEMM epilogue (R5) ----------
__global__ __launch_bounds__(192) void k_conv_x(
    const float* __restrict__ xsrc, const float* __restrict__ W,
    const float* __restrict__ b, const float* __restrict__ dis,
    const int* __restrict__ rowptr, const int2* __restrict__ csr,
    float* __restrict__ out)
{
    __shared__ float sAgg[FEAT];
    __shared__ int2  sE[192];
    __shared__ float sB[COUT];

    const int n = blockIdx.x;
    const int t = threadIdx.x;
    if (t < COUT) sB[t] = b[t];

    const int start = rowptr[n];
    const int end   = rowptr[n + 1];
    const float dn  = dis[n];
    const float selfw = dn * dn;

    const f32x4* xb = (const f32x4*)xsrc;
    f32x4 v = xb[(size_t)n * QROW + t];
    float a0 = selfw * v.x, a1 = selfw * v.y, a2 = selfw * v.z, a3 = selfw * v.w;

    for (int base = start; base < end; base += 192) {
        int cnt = end - base; if (cnt > 192) cnt = 192;
        __syncthreads();
        if (t < cnt) sE[t] = csr[base + t];
        __syncthreads();
        for (int j = 0; j < cnt; ++j) {
            int s    = sE[j].x;
            float w  = __int_as_float(sE[j].y);
            f32x4 u = xb[(size_t)s * QROW + t];
            a0 = fmaf(w, u.x, a0); a1 = fmaf(w, u.y, a1);
            a2 = fmaf(w, u.z, a2); a3 = fmaf(w, u.w, a3);
        }
    }

    float4 av; av.x = a0; av.y = a1; av.z = a2; av.w = a3;
    *((float4*)&sAgg[4 * t]) = av;
    __syncthreads();

    const int co  = t & 63;
    const int tg  = t >> 6;
    const int tt0 = tg * 4;
    float o0 = sB[co], o1 = o0, o2 = o0, o3 = o0;
#pragma unroll
    for (int c = 0; c < CIN; ++c) {
        float wv = W[c * COUT + co];
        o0 = fmaf(wv, sAgg[c * TT + tt0    ], o0);
        o1 = fmaf(wv, sAgg[c * TT + tt0 + 1], o1);
        o2 = fmaf(wv, sAgg[c * TT + tt0 + 2], o2);
        o3 = fmaf(wv, sAgg[c * TT + tt0 + 3], o3);
    }
    o0 = fmaxf(o0, 0.0f); o1 = fmaxf(o1, 0.0f);
    o2 = fmaxf(o2, 0.0f); o3 = fmaxf(o3, 0.0f);

    __syncthreads();
    float4 ov; ov.x = o0; ov.y = o1; ov.z = o2; ov.w = o3;
    *((float4*)&sAgg[co * TT + tt0]) = ov;
    __syncthreads();
    f32x4 r = *((const f32x4*)&sAgg[4 * t]);
    __builtin_nontemporal_store(r, (f32x4*)(out + (size_t)n * FEAT + 4 * t));
}

// ---------- launch ----------
extern "C" void kernel_launch(void* const* d_in, const int* in_sizes, int n_in,
                              void* d_out, int out_size, void* d_ws, size_t ws_size,
                              hipStream_t stream) {
    const float* x   = (const float*)d_in[0];
    const int*   ei  = (const int*)d_in[1];
    const float* ea  = (const float*)d_in[2];
    const float* W   = (const float*)d_in[3];
    const float* b   = (const float*)d_in[4];
    float* out = (float*)d_out;

    const int E = in_sizes[2];
    const int N = in_sizes[0] / FEAT;
    const int* src = ei;
    const int* dst = ei + E;

    size_t off = 0;
    char* ws = (char*)d_ws;
    auto alloc = [&](size_t bytes) -> char* {
        char* p = ws + off;
        off = (off + bytes + 15) & ~(size_t)15;
        return p;
    };
    u64*   deg64   = (u64*)  alloc((size_t)N * 8);
    float* dis     = (float*)alloc((size_t)N * 4);
    int*   rowptr  = (int*)  alloc((size_t)(N + 1) * 4);
    int*   cursor  = (int*)  alloc((size_t)N * 4);
    int*   partial = (int*)  alloc(4096);
    int2*  csr     = (int2*) alloc((size_t)E * 8);
    unsigned short* yh = (unsigned short*)alloc((size_t)N * FEAT * 2);
    const bool use_bf16 = (off <= ws_size);

    int nb_n   = (N + 255) / 256;    // 196 for N=50000; must be <= 256
    int nb_e   = (E + 255) / 256;
    int nb_e384 = (E + 383) / 384;

    (void)hipMemsetAsync(deg64, 0, (size_t)N * 8, stream);
    if (use_bf16) {
        int nbY = 1280;
        k_ygemm_deg<<<nbY + nb_e384, 384, 0, stream>>>(x, W, yh, N, nbY,
                                                       dst, ea, deg64, E);
    } else {
        k_ygemm_deg<<<nb_e384, 384, 0, stream>>>(x, W, nullptr, N, 0,
                                                 dst, ea, deg64, E);
    }
    k_disred   <<<nb_n, 256, 0, stream>>>(deg64, dis, partial, N);
    k_scanwrite<<<nb_n, 256, 0, stream>>>(deg64, partial, nb_n, rowptr, cursor, N);
    k_fill     <<<nb_e, 256, 0, stream>>>(src, dst, ea, dis, cursor, csr, E);
    if (use_bf16)
        k_conv_y<<<N, 192, 0, stream>>>(yh, b, dis, rowptr, csr, out);
    else
        k_conv_x<<<N, 192, 0, stream>>>(x, W, b, dis, rowptr, csr, out);
}

// Round 8
// 311.286 us; speedup vs baseline: 2.3524x; 1.3573x over previous
//
#include <hip/hip_runtime.h>

#define CIN   64
#define COUT  64
#define TT    12
#define FEAT  (CIN * TT)   // 768
#define QROW  (FEAT / 4)   // 192 uint2 (4 bf16) per row

typedef unsigned int uint32;
typedef unsigned long long u64;
typedef float  __attribute__((ext_vector_type(4))) f32x4;

#define DEG_SCALE 1048576.0f   // 2^20 fixed point for edge-weight sums

__device__ __forceinline__ void cvt_range(const f32x4* __restrict__ x,
                                          uint2* __restrict__ xh,
                                          int qlo, int qhi, int tid, int stride) {
    for (int i = qlo + tid; i < qhi; i += stride) {
        f32x4 v = __builtin_nontemporal_load(&x[i]);   // read-once stream
        uint32 u0 = __float_as_uint(v.x), u1 = __float_as_uint(v.y);
        uint32 u2 = __float_as_uint(v.z), u3 = __float_as_uint(v.w);
        u0 = (u0 + 0x7fffu + ((u0 >> 16) & 1)) >> 16;
        u1 = (u1 + 0x7fffu + ((u1 >> 16) & 1)) >> 16;
        u2 = (u2 + 0x7fffu + ((u2 >> 16) & 1)) >> 16;
        u3 = (u3 + 0x7fffu + ((u3 >> 16) & 1)) >> 16;
        uint2 o; o.x = u0 | (u1 << 16); o.y = u2 | (u3 << 16);
        xh[i] = o;
    }
}

// ---------- L1: degree atomics + cvt half A ----------
__global__ __launch_bounds__(256) void k_deg_cvt(
    const f32x4* __restrict__ x, uint2* __restrict__ xh, int qlo, int qhi, int nbCvt,
    const int* __restrict__ dst, const float* __restrict__ ea,
    u64* __restrict__ deg64, int e_cnt)
{
    int bid = blockIdx.x;
    if (bid < nbCvt) {
        cvt_range(x, xh, qlo, qhi, bid * 256 + threadIdx.x, nbCvt * 256);
    } else {
        int e = (bid - nbCvt) * 256 + threadIdx.x;
        if (e < e_cnt) {
            u64 v = ((u64)1 << 32) | (u64)(uint32)(ea[e] * DEG_SCALE + 0.5f);
            atomicAdd(&deg64[dst[e]], v);
        }
    }
}

// ---------- L2: dis = rsqrt(1 + sum_ea); block-reduce cnt into partial[] ----------
__global__ __launch_bounds__(256) void k_disred(const u64* __restrict__ deg64,
                                                float* __restrict__ dis,
                                                int* __restrict__ partial, int n) {
    __shared__ int red[256];
    int t = threadIdx.x;
    int i = blockIdx.x * 256 + t;
    int cnt = 0;
    if (i < n) {
        u64 v = deg64[i];
        cnt = (int)(v >> 32);
        dis[i] = rsqrtf(1.0f + (float)(uint32)v * (1.0f / DEG_SCALE));
    }
    red[t] = cnt;
    __syncthreads();
    for (int off = 128; off > 0; off >>= 1) {
        if (t < off) red[t] += red[t + off];
        __syncthreads();
    }
    if (t == 0) partial[blockIdx.x] = red[0];
}

// ---------- L3: per-element scan; each block redundantly reduces partial[] ----------
// nb (number of partials) must be <= 256
__global__ __launch_bounds__(256) void k_scanwrite(const u64* __restrict__ deg64,
                                                   const int* __restrict__ partial,
                                                   int nb,
                                                   int* __restrict__ rowptr,
                                                   int* __restrict__ cursor, int n) {
    __shared__ int tmp[256];
    __shared__ int pred[256];
    int t = threadIdx.x;
    int bid = blockIdx.x;
    int i = bid * 256 + t;

    int pv = (t < nb) ? partial[t] : 0;
    pred[t] = (t < bid) ? pv : 0;
    int v = (i < n) ? (int)(deg64[i] >> 32) : 0;
    tmp[t] = v;
    __syncthreads();
    for (int off = 128; off > 0; off >>= 1) {
        if (t < off) pred[t] += pred[t + off];
        __syncthreads();
    }
    for (int off = 1; off < 256; off <<= 1) {
        int u = (t >= off) ? tmp[t - off] : 0;
        __syncthreads();
        tmp[t] += u;
        __syncthreads();
    }
    int blockOff = pred[0];
    int excl = tmp[t] - v + blockOff;
    if (i < n) { rowptr[i] = excl; cursor[i] = excl; }
    if (bid == nb - 1 && t == 255) rowptr[n] = blockOff + tmp[255];
}

// ---------- L4: scatter edges into CSR slots + cvt half B ----------
__global__ __launch_bounds__(256) void k_fill_cvt(
    const f32x4* __restrict__ x, uint2* __restrict__ xh, int qlo, int qhi, int nbCvt,
    const int* __restrict__ src, const int* __restrict__ dst,
    const float* __restrict__ ea, const float* __restrict__ dis,
    int* __restrict__ cursor, int2* __restrict__ csr, int e_cnt)
{
    int bid = blockIdx.x;
    if (bid < nbCvt) {
        cvt_range(x, xh, qlo, qhi, bid * 256 + threadIdx.x, nbCvt * 256);
    } else {
        int e = (bid - nbCvt) * 256 + threadIdx.x;
        if (e < e_cnt) {
            int s = src[e], d = dst[e];
            int pos = atomicAdd(&cursor[d], 1);
            float w = dis[s] * ea[e] * dis[d];
            int2 p; p.x = s; p.y = __float_as_int(w);
            csr[pos] = p;
        }
    }
}

// ---------- fused aggregate + GEMM + bias + ReLU (R5 proven structure) ----------
// one block per node, 192 threads; thread t owns features [4t, 4t+4)
template <int BF16>
__global__ __launch_bounds__(192) void k_conv(
    const void* __restrict__ xsrc, const float* __restrict__ W,
    const float* __restrict__ b, const float* __restrict__ dis,
    const int* __restrict__ rowptr, const int2* __restrict__ csr,
    float* __restrict__ out)
{
    __shared__ float sAgg[FEAT];   // 3 KB
    __shared__ int2  sE[192];      // 1.5 KB
    __shared__ float sB[COUT];

    const int n = blockIdx.x;
    const int t = threadIdx.x;
    if (t < COUT) sB[t] = b[t];

    const int start = rowptr[n];
    const int end   = rowptr[n + 1];
    const float dn  = dis[n];
    const float selfw = dn * dn;

    float a0, a1, a2, a3;
    if (BF16) {
        const uint2* xb = (const uint2*)xsrc;
        uint2 v = xb[(size_t)n * QROW + t];
        a0 = selfw * __uint_as_float(v.x << 16);
        a1 = selfw * __uint_as_float(v.x & 0xffff0000u);
        a2 = selfw * __uint_as_float(v.y << 16);
        a3 = selfw * __uint_as_float(v.y & 0xffff0000u);
    } else {
        const f32x4* xb = (const f32x4*)xsrc;
        f32x4 v = xb[(size_t)n * QROW + t];
        a0 = selfw * v.x; a1 = selfw * v.y; a2 = selfw * v.z; a3 = selfw * v.w;
    }

    for (int base = start; base < end; base += 192) {
        int cnt = end - base; if (cnt > 192) cnt = 192;
        __syncthreads();
        if (t < cnt) sE[t] = csr[base + t];
        __syncthreads();
        for (int j = 0; j < cnt; ++j) {
            int s    = sE[j].x;
            float w  = __int_as_float(sE[j].y);
            if (BF16) {
                const uint2* xb = (const uint2*)xsrc;
                uint2 v = xb[(size_t)s * QROW + t];
                a0 = fmaf(w, __uint_as_float(v.x << 16),         a0);
                a1 = fmaf(w, __uint_as_float(v.x & 0xffff0000u), a1);
                a2 = fmaf(w, __uint_as_float(v.y << 16),         a2);
                a3 = fmaf(w, __uint_as_float(v.y & 0xffff0000u), a3);
            } else {
                const f32x4* xb = (const f32x4*)xsrc;
                f32x4 v = xb[(size_t)s * QROW + t];
                a0 = fmaf(w, v.x, a0); a1 = fmaf(w, v.y, a1);
                a2 = fmaf(w, v.z, a2); a3 = fmaf(w, v.w, a3);
            }
        }
    }

    float4 av; av.x = a0; av.y = a1; av.z = a2; av.w = a3;
    *((float4*)&sAgg[4 * t]) = av;
    __syncthreads();

    const int co  = t & 63;
    const int tg  = t >> 6;              // wave-uniform
    const int tt0 = tg * 4;
    float o0 = sB[co], o1 = o0, o2 = o0, o3 = o0;
#pragma unroll
    for (int c = 0; c < CIN; ++c) {
        float wv = W[c * COUT + co];     // hot 16 KB in L1/L2
        o0 = fmaf(wv, sAgg[c * TT + tt0    ], o0);
        o1 = fmaf(wv, sAgg[c * TT + tt0 + 1], o1);
        o2 = fmaf(wv, sAgg[c * TT + tt0 + 2], o2);
        o3 = fmaf(wv, sAgg[c * TT + tt0 + 3], o3);
    }
    o0 = fmaxf(o0, 0.0f); o1 = fmaxf(o1, 0.0f);
    o2 = fmaxf(o2, 0.0f); o3 = fmaxf(o3, 0.0f);

    __syncthreads();
    float4 ov; ov.x = o0; ov.y = o1; ov.z = o2; ov.w = o3;
    *((float4*)&sAgg[co * TT + tt0]) = ov;
    __syncthreads();
    f32x4 r = *((const f32x4*)&sAgg[4 * t]);
    __builtin_nontemporal_store(r, (f32x4*)(out + (size_t)n * FEAT + 4 * t));
}

// ---------- launch ----------
extern "C" void kernel_launch(void* const* d_in, const int* in_sizes, int n_in,
                              void* d_out, int out_size, void* d_ws, size_t ws_size,
                              hipStream_t stream) {
    const float* x   = (const float*)d_in[0];
    const int*   ei  = (const int*)d_in[1];
    const float* ea  = (const float*)d_in[2];
    const float* W   = (const float*)d_in[3];
    const float* b   = (const float*)d_in[4];
    float* out = (float*)d_out;

    const int E = in_sizes[2];
    const int N = in_sizes[0] / FEAT;
    const int* src = ei;
    const int* dst = ei + E;

    size_t off = 0;
    char* ws = (char*)d_ws;
    auto alloc = [&](size_t bytes) -> char* {
        char* p = ws + off;
        off = (off + bytes + 15) & ~(size_t)15;
        return p;
    };
    u64*   deg64   = (u64*)  alloc((size_t)N * 8);
    float* dis     = (float*)alloc((size_t)N * 4);
    int*   rowptr  = (int*)  alloc((size_t)(N + 1) * 4);
    int*   cursor  = (int*)  alloc((size_t)N * 4);
    int*   partial = (int*)  alloc(4096);
    int2*  csr     = (int2*) alloc((size_t)E * 8);
    unsigned short* xh = (unsigned short*)alloc((size_t)N * FEAT * 2);
    const bool use_bf16 = (off <= ws_size);

    int nb_n   = (N + 255) / 256;    // 196 for N=50000; must be <= 256
    int nb_e   = (E + 255) / 256;
    int nquads = (N * FEAT) / 4;
    int halfQ  = nquads / 2;
    int nbCvt  = use_bf16 ? 1024 : 0;

    (void)hipMemsetAsync(deg64, 0, (size_t)N * 8, stream);
    // L1: deg atomics + cvt quads [0, halfQ)
    k_deg_cvt  <<<nbCvt + nb_e, 256, 0, stream>>>((const f32x4*)x, (uint2*)xh,
                                                  0, halfQ, nbCvt, dst, ea, deg64, E);
    k_disred   <<<nb_n, 256, 0, stream>>>(deg64, dis, partial, N);
    k_scanwrite<<<nb_n, 256, 0, stream>>>(deg64, partial, nb_n, rowptr, cursor, N);
    // L4: CSR fill + cvt quads [halfQ, nquads)
    k_fill_cvt <<<nbCvt + nb_e, 256, 0, stream>>>((const f32x4*)x, (uint2*)xh,
                                                  halfQ, nquads, nbCvt,
                                                  src, dst, ea, dis, cursor, csr, E);
    if (use_bf16)
        k_conv<1><<<N, 192, 0, stream>>>(xh, W, b, dis, rowptr, csr, out);
    else
        k_conv<0><<<N, 192, 0, stream>>>(x,  W, b, dis, rowptr, csr, out);
}